// Round 11
// baseline (12911.461 us; speedup 1.0000x reference)
//
#include <hip/hip_runtime.h>

// RNN echo-state scan on MI355X — round 11: r9 protocol + arrival-driven
// chunked consumption.
// Protocol (UNCHANGED from r9, proven r2/r6/r9): sc1 write-through publish ->
// per-wave vmcnt(0) drain -> agent-atomic counter post; consumer agent-atomic
// poll -> acquire-fence (buffer_inv) -> plain batched loads.
// NEW (perf only): instead of waiting for ALL 16 producers then loading the
// whole A-tile, each wave polls all 16 flags, and consumes producers AS THEY
// ARRIVE: ballot -> `newly` mask -> one fence per batch -> static-unrolled
// predicated loads (one vmcnt drain) -> their 4 MFMAs. Early chunks overlap
// the wait for stragglers; exposed tail = last post -> observe -> fence ->
// 4KB chunk -> 4 MFMAs. Chunk cache-lines are disjoint across producers, and
// every load batch is fence-preceded => same coherence invariant as r9.
// Geometry = r9: 8 groups x 16 WGs x 128 thr; 8 batches/group; 64 cols/WG;
// W f16 single-plane LDS (139,264 B); x hi/lo f16 split; f16 exchange.

#define TT    2048
#define BB    64
#define NIN   64
#define NRECN 1024
#define KTOT  1088
#define NGRP  8
#define WPGRP 16
#define NWG   128
#define NOISE_STD 0.001f

typedef __attribute__((ext_vector_type(8))) _Float16 half8;
typedef __attribute__((ext_vector_type(4))) float f32x4;

// Write-through, agent-coherent 2B store (proven r2/r6/r9).
__device__ __forceinline__ void st_h_sc1(_Float16* p, unsigned short u) {
  unsigned v = u;
  asm volatile("global_store_short %0, %1, off sc1" :: "v"(p), "v"(v) : "memory");
}
__device__ __forceinline__ void split8h(const f32x4& v0, const f32x4& v1,
                                        half8& hh, half8& hl) {
  #pragma unroll
  for (int j = 0; j < 4; ++j) {
    _Float16 h = (_Float16)v0[j];
    hh[j] = h; hl[j] = (_Float16)(v0[j] - (float)h);
  }
  #pragma unroll
  for (int j = 0; j < 4; ++j) {
    _Float16 h = (_Float16)v1[j];
    hh[4 + j] = h; hl[4 + j] = (_Float16)(v1[j] - (float)h);
  }
}

// 16B plain load (L2-cached), immediate offset (0 or 64 here).
#define LDA16(V, P, OFF) \
  asm volatile("global_load_dwordx4 %0, %1, off offset:%c2" \
               : "=&v"(V) : "v"(P), "n"(OFF))

#define MFMA16 __builtin_amdgcn_mfma_f32_16x16x32_f16

__global__ __launch_bounds__(128, 1) void rnn_scan_kernel(
    const float* __restrict__ x, const float* __restrict__ W_ih,
    const float* __restrict__ W_hh, const float* __restrict__ noise,
    float* __restrict__ out, int* __restrict__ flags,
    _Float16* __restrict__ th)
{
  extern __shared__ _Float16 smem[];   // W f16, sub-chunk-major [136][64][8]

  const int wg = blockIdx.x, grp = wg & 7, gidx = wg >> 3;
  const int tid = threadIdx.x, lane = tid & 63, wv = tid >> 6;
  const int l15 = lane & 15, g4 = lane >> 4;

  // one-time: W slice (cols gidx*64..+64, K=1088) -> LDS f16
  for (int idx = tid; idx < 64 * KTOT; idx += 128) {
    int nr = idx / KTOT, k = idx - nr * KTOT;
    int ng = gidx * 64 + nr;
    float v = (k < NRECN) ? W_hh[(size_t)ng * NRECN + k]
                          : W_ih[(size_t)ng * NIN + (k - NRECN)];
    smem[(k >> 3) * 512 + nr * 8 + (k & 7)] = (_Float16)v;
  }
  __syncthreads();

  int* flags_g = flags + grp * WPGRP * 16;      // 16 counters x 64B per group
  const _Float16* whp0 = smem + g4 * 512 + (wv * 32 + l15) * 8; // +c*2048/chunk
  const _Float16* whp1 = whp0 + 128;            // second 16-col fragment
  _Float16* thg = th + grp * (2 * 16 * 1024);   // [buf][16 rows][1024] f16
  const int b_eff = grp * 8 + (l15 & 7);        // pad A rows 8..15 clamp
  const float* xrow = x + (size_t)b_eff * TT * NIN;
  const int col0 = gidx * 64 + wv * 32 + l15, col1 = col0 + 16;

  for (int t = 0; t < TT; ++t) {
    // ---- x part (K chunks 32,33), f16 hi/lo split — before any polling
    const float* xp = xrow + (size_t)t * NIN + g4 * 8;
    f32x4 v0 = *(const f32x4*)xp,        v1 = *(const f32x4*)(xp + 4);
    f32x4 v2 = *(const f32x4*)(xp + 32), v3 = *(const f32x4*)(xp + 36);
    const float nz0 = noise[(size_t)t * NRECN + col0] * NOISE_STD;
    const float nz1 = noise[(size_t)t * NRECN + col1] * NOISE_STD;

    f32x4 P0{0,0,0,0}, P1{0,0,0,0}, Q0{0,0,0,0}, Q1{0,0,0,0};
    {
      half8 xh, xl;
      split8h(v0, v1, xh, xl);
      half8 b0 = *(const half8*)(whp0 + 32 * 2048);
      half8 b1 = *(const half8*)(whp1 + 32 * 2048);
      P0 = MFMA16(xh, b0, P0, 0,0,0); P1 = MFMA16(xh, b1, P1, 0,0,0);
      Q0 = MFMA16(xl, b0, Q0, 0,0,0); Q1 = MFMA16(xl, b1, Q1, 0,0,0);
      split8h(v2, v3, xh, xl);
      b0 = *(const half8*)(whp0 + 33 * 2048);
      b1 = *(const half8*)(whp1 + 33 * 2048);
      P0 = MFMA16(xh, b0, P0, 0,0,0); P1 = MFMA16(xh, b1, P1, 0,0,0);
      Q0 = MFMA16(xl, b0, Q0, 0,0,0); Q1 = MFMA16(xl, b1, Q1, 0,0,0);
    }

    // ---- recurrent part: consume producers as they arrive
    if (t > 0) {
      const int target = t << 1;                 // 2 posts/WG/step (r9)
      const _Float16* abase = thg + (t & 1) * 16384 + l15 * 1024 + g4 * 8;
      unsigned done = 0;
      while (done != 0xFFFFu) {
        int fv = 0x7FFFFFFF;                     // lanes >=16 always "ready"
        if (lane < WPGRP)
          fv = __hip_atomic_load(&flags_g[lane * 16], __ATOMIC_RELAXED,
                                 __HIP_MEMORY_SCOPE_AGENT);
        unsigned long long rdy = __ballot(fv >= target);
        unsigned newly = ((unsigned)rdy & 0xFFFFu) & ~done;
        if (!newly) continue;
        __builtin_amdgcn_fence(__ATOMIC_ACQUIRE, "agent");  // r9-proven order

        half8 aA[16], aB[16];                    // static-indexed (rule #20)
        #pragma unroll
        for (int j = 0; j < 16; ++j)
          if (newly & (1u << j)) {
            const _Float16* pj = abase + j * 64; // producer j = K-chunks 2j,2j+1
            LDA16(aA[j], pj, 0);
            LDA16(aB[j], pj, 64);
          }
        asm volatile("s_waitcnt vmcnt(0)" ::: "memory");
        __builtin_amdgcn_sched_barrier(0);       // rule #18

        #pragma unroll
        for (int j = 0; j < 16; ++j)
          if (newly & (1u << j)) {
            half8 b0 = *(const half8*)(whp0 + (2 * j) * 2048);
            half8 b1 = *(const half8*)(whp1 + (2 * j) * 2048);
            half8 b2 = *(const half8*)(whp0 + (2 * j + 1) * 2048);
            half8 b3 = *(const half8*)(whp1 + (2 * j + 1) * 2048);
            P0 = MFMA16(aA[j], b0, P0, 0,0,0);
            P1 = MFMA16(aA[j], b1, P1, 0,0,0);
            Q0 = MFMA16(aB[j], b2, Q0, 0,0,0);
            Q1 = MFMA16(aB[j], b3, Q1, 0,0,0);
          }
        done |= newly;
      }
    }

    // ---- epilogue: h, tanh, f16 sc1 publish (rows 0..7 valid; 8..15 pad)
    f32x4 h0 = P0 + Q0, h1 = P1 + Q1;
    _Float16* ob = thg + ((t + 1) & 1) * 16384;
    float ho0[4], ho1[4];
    #pragma unroll
    for (int r = 0; r < 4; ++r) {
      const int mr = g4 * 4 + r;                 // C-frag row (m89 layout)
      float a0 = h0[r] + nz0, a1 = h1[r] + nz1;
      ho0[r] = a0; ho1[r] = a1;
      if (mr < 8) {
        float t0 = 1.f - 2.f / (__expf(2.f * a0) + 1.f);
        float t1 = 1.f - 2.f / (__expf(2.f * a1) + 1.f);
        st_h_sc1(ob + mr * 1024 + col0,
                 __builtin_bit_cast(unsigned short, (_Float16)t0));
        st_h_sc1(ob + mr * 1024 + col1,
                 __builtin_bit_cast(unsigned short, (_Float16)t1));
      }
    }
    asm volatile("s_waitcnt vmcnt(0)" ::: "memory");  // my th stores at MALL
    if (lane == 0)
      __hip_atomic_fetch_add(&flags_g[gidx * 16], 1, __ATOMIC_RELAXED,
                             __HIP_MEMORY_SCOPE_AGENT);

    // ---- outputs, off the critical path (after flag post)
    if (grp == NGRP - 1 || t == TT - 1) {
      #pragma unroll
      for (int r = 0; r < 4; ++r) {
        const int mr = g4 * 4 + r;
        if (mr < 8) {
          const int br = grp * 8 + mr;
          if (br == BB - 1) {
            out[(size_t)col0 * TT + t] = ho0[r];
            out[(size_t)col1 * TT + t] = ho1[r];
          }
          if (t == TT - 1) {
            out[(size_t)NRECN * TT + (size_t)br * NRECN + col0] = ho0[r];
            out[(size_t)NRECN * TT + (size_t)br * NRECN + col1] = ho1[r];
          }
        }
      }
    }
  }
}

extern "C" void kernel_launch(void* const* d_in, const int* in_sizes, int n_in,
                              void* d_out, int out_size, void* d_ws, size_t ws_size,
                              hipStream_t stream) {
  const float* x     = (const float*)d_in[0];
  const float* W_ih  = (const float*)d_in[1];
  const float* W_hh  = (const float*)d_in[2];
  const float* noise = (const float*)d_in[3];
  float* out = (float*)d_out;

  char* ws = (char*)d_ws;
  int* flags = (int*)ws;                         // 8 grp x 16 ctr x 64B = 8KB
  _Float16* th = (_Float16*)(ws + 8192);         // [8][2][16][1024] f16, 512KB
  // ws usage: 8192 + 524288 = 532,480 bytes.
  // th pad rows 8..15 are never written and feed only discarded C rows.

  (void)hipMemsetAsync(flags, 0, 8192, stream);  // deterministic replays

  const size_t lds_bytes = (size_t)136 * 64 * 8 * sizeof(_Float16); // 139,264
  (void)hipFuncSetAttribute((const void*)rnn_scan_kernel,
                            hipFuncAttributeMaxDynamicSharedMemorySize,
                            (int)lds_bytes);

  rnn_scan_kernel<<<dim3(NWG), dim3(128), lds_bytes, stream>>>(
      x, W_ih, W_hh, noise, out, flags, th);
}

// Round 12
// 10789.574 us; speedup vs baseline: 1.1967x; 1.1967x over previous
//
#include <hip/hip_runtime.h>

// RNN echo-state scan on MI355X — round 12.
// Protocol = r9-proven skeleton: sc1 write-through publish -> syncthreads
// (vmcnt drain) -> ONE agent-atomic counter post per WG; consumer tid0 poll of
// ONE per-group counter -> wave0-elected acquire-fence -> syncthreads -> plain
// batched loads with counted vmcnt consume.
// New vs r11 (all perf-only):
//  * operand-swapped MFMAs: C' lane = batch, regs = 4 consecutive cols ->
//    publish = 2x 8B coalesced dwordx2 sc1 stores per lane (was 16x 2B).
//  * 8-row th tile, A-row dup via (l15&7): no 16KB/step zero-pad refetch.
//  * one fence per WG (wave0) + one flag counter per group (16 posts -> 1 line).
//  * counted vmcnt(24/16/8/0) A-consume; <=128 A VGPRs live, no spill.

#define TT    2048
#define BB    64
#define NIN   64
#define NRECN 1024
#define KTOT  1088
#define NGRP  8
#define WPGRP 16
#define NWG   128
#define NOISE_STD 0.001f

typedef __attribute__((ext_vector_type(8))) _Float16 half8;
typedef __attribute__((ext_vector_type(4))) float f32x4;
typedef __attribute__((ext_vector_type(2))) unsigned int u32x2;

// Write-through, agent-coherent 8B store (sc1 path proven r2/r6/r9).
__device__ __forceinline__ void st_d2_sc1(void* p, u32x2 w) {
  asm volatile("global_store_dwordx2 %0, %1, off sc1" :: "v"(p), "v"(w) : "memory");
}
__device__ __forceinline__ unsigned pk2h(float a, float b) {
  unsigned short ua = __builtin_bit_cast(unsigned short, (_Float16)a);
  unsigned short ub = __builtin_bit_cast(unsigned short, (_Float16)b);
  return (unsigned)ua | ((unsigned)ub << 16);
}
__device__ __forceinline__ void split8h(const f32x4& v0, const f32x4& v1,
                                        half8& hh, half8& hl) {
  #pragma unroll
  for (int j = 0; j < 4; ++j) {
    _Float16 h = (_Float16)v0[j];
    hh[j] = h; hl[j] = (_Float16)(v0[j] - (float)h);
  }
  #pragma unroll
  for (int j = 0; j < 4; ++j) {
    _Float16 h = (_Float16)v1[j];
    hh[4 + j] = h; hl[4 + j] = (_Float16)(v1[j] - (float)h);
  }
}

// 16B plain load (L2-cached), immediate offset (max 1984 < 4096).
#define LDA16(V, P, OFF) \
  asm volatile("global_load_dwordx4 %0, %1, off offset:%c2" \
               : "=&v"(V) : "v"(P), "n"(OFF))
#define WAITV(N) asm volatile("s_waitcnt vmcnt(" #N ")" ::: "memory")

#define MFMA16 __builtin_amdgcn_mfma_f32_16x16x32_f16

// One K-chunk: swapped operands (W = A-operand, th = B-operand).
#define ACHUNK(c) {                                            \
    half8 b0 = *(const half8*)(whp0 + (c) * 2048);             \
    half8 b1 = *(const half8*)(whp1 + (c) * 2048);             \
    if ((c) & 1) {                                             \
      Q0 = MFMA16(b0, A[c], Q0, 0, 0, 0);                      \
      Q1 = MFMA16(b1, A[c], Q1, 0, 0, 0);                      \
    } else {                                                   \
      P0 = MFMA16(b0, A[c], P0, 0, 0, 0);                      \
      P1 = MFMA16(b1, A[c], P1, 0, 0, 0);                      \
    } }

__global__ __launch_bounds__(128, 1) void rnn_scan_kernel(
    const float* __restrict__ x, const float* __restrict__ W_ih,
    const float* __restrict__ W_hh, const float* __restrict__ noise,
    float* __restrict__ out, int* __restrict__ flags,
    _Float16* __restrict__ th)
{
  extern __shared__ _Float16 smem[];   // W f16, sub-chunk-major [136][64][8]

  const int wg = blockIdx.x, grp = wg & 7, gidx = wg >> 3;
  const int tid = threadIdx.x, lane = tid & 63, wv = tid >> 6;
  const int l15 = lane & 15, g4 = lane >> 4;

  // one-time: W slice (cols gidx*64..+64, K=1088) -> LDS f16 (proven r9)
  for (int idx = tid; idx < 64 * KTOT; idx += 128) {
    int nr = idx / KTOT, k = idx - nr * KTOT;
    int ng = gidx * 64 + nr;
    float v = (k < NRECN) ? W_hh[(size_t)ng * NRECN + k]
                          : W_ih[(size_t)ng * NIN + (k - NRECN)];
    smem[(k >> 3) * 512 + nr * 8 + (k & 7)] = (_Float16)v;
  }
  __syncthreads();

  int* ctr = flags + grp * 16;                  // ONE counter per group (64B apart)
  const _Float16* whp0 = smem + g4 * 512 + (wv * 32 + l15) * 8; // +c*2048/chunk
  const _Float16* whp1 = whp0 + 128;            // second 16-col W fragment
  _Float16* thg = th + grp * (2 * 8 * 1024);    // [buf][8 batch][1024] f16
  const int b_eff = grp * 8 + (l15 & 7);        // A-rows 8..15 dup (C cols discarded)
  const float* xrow = x + (size_t)b_eff * TT * NIN;
  const int cB = gidx * 64 + wv * 32 + g4 * 4;  // lane's 4-col base (tile0)

  for (int t = 0; t < TT; ++t) {
    // ---- pre-poll: x + noise loads, x-part MFMAs (regs survive the fence)
    const float* xp = xrow + (size_t)t * NIN + g4 * 8;
    f32x4 v0 = *(const f32x4*)xp,        v1 = *(const f32x4*)(xp + 4);
    f32x4 v2 = *(const f32x4*)(xp + 32), v3 = *(const f32x4*)(xp + 36);
    f32x4 nz0 = *(const f32x4*)(noise + (size_t)t * NRECN + cB);
    f32x4 nz1 = *(const f32x4*)(noise + (size_t)t * NRECN + cB + 16);
    #pragma unroll
    for (int r = 0; r < 4; ++r) { nz0[r] *= NOISE_STD; nz1[r] *= NOISE_STD; }

    f32x4 P0{0,0,0,0}, P1{0,0,0,0}, Q0{0,0,0,0}, Q1{0,0,0,0};
    {
      half8 xh, xl;
      split8h(v0, v1, xh, xl);
      half8 b0 = *(const half8*)(whp0 + 32 * 2048);
      half8 b1 = *(const half8*)(whp1 + 32 * 2048);
      P0 = MFMA16(b0, xh, P0, 0,0,0); P1 = MFMA16(b1, xh, P1, 0,0,0);
      Q0 = MFMA16(b0, xl, Q0, 0,0,0); Q1 = MFMA16(b1, xl, Q1, 0,0,0);
      split8h(v2, v3, xh, xl);
      b0 = *(const half8*)(whp0 + 33 * 2048);
      b1 = *(const half8*)(whp1 + 33 * 2048);
      P0 = MFMA16(b0, xh, P0, 0,0,0); P1 = MFMA16(b1, xh, P1, 0,0,0);
      Q0 = MFMA16(b0, xl, Q0, 0,0,0); Q1 = MFMA16(b1, xl, Q1, 0,0,0);
    }

    // ---- recurrent part (r9-proven protocol; elected poll/fence)
    if (t > 0) {
      const int target = t * WPGRP;
      if (tid == 0) {
        while (__hip_atomic_load(ctr, __ATOMIC_RELAXED,
                                 __HIP_MEMORY_SCOPE_AGENT) < target) { }
      }
      if (wv == 0)
        __builtin_amdgcn_fence(__ATOMIC_ACQUIRE, "agent");  // one inv per WG
      __syncthreads();   // wave1 held here until fence done (same-CU L1/L2)

      const _Float16* abase = thg + (t & 1) * 8192 + (l15 & 7) * 1024 + g4 * 8;
      half8 A[32];
      #pragma unroll
      for (int c = 0; c < 32; ++c) LDA16(A[c], abase, c * 64);
      WAITV(24); __builtin_amdgcn_sched_barrier(0);
      #pragma unroll
      for (int c = 0; c < 8; ++c) ACHUNK(c);
      WAITV(16); __builtin_amdgcn_sched_barrier(0);
      #pragma unroll
      for (int c = 8; c < 16; ++c) ACHUNK(c);
      WAITV(8);  __builtin_amdgcn_sched_barrier(0);
      #pragma unroll
      for (int c = 16; c < 24; ++c) ACHUNK(c);
      WAITV(0);  __builtin_amdgcn_sched_barrier(0);
      #pragma unroll
      for (int c = 24; c < 32; ++c) ACHUNK(c);
    }

    // ---- epilogue: h (lane=batch, regs=4 consecutive cols), tanh, publish
    f32x4 h0 = (P0 + Q0) + nz0;
    f32x4 h1 = (P1 + Q1) + nz1;
    _Float16* ob = thg + ((t + 1) & 1) * 8192;
    float tv0[4], tv1[4];
    #pragma unroll
    for (int r = 0; r < 4; ++r) {
      tv0[r] = 1.f - 2.f / (__expf(2.f * h0[r]) + 1.f);
      tv1[r] = 1.f - 2.f / (__expf(2.f * h1[r]) + 1.f);
    }
    if (l15 < 8) {                               // lanes 8..15 = dup batches
      u32x2 w0, w1;
      w0[0] = pk2h(tv0[0], tv0[1]); w0[1] = pk2h(tv0[2], tv0[3]);
      w1[0] = pk2h(tv1[0], tv1[1]); w1[1] = pk2h(tv1[2], tv1[3]);
      st_d2_sc1(ob + l15 * 1024 + cB, w0);
      st_d2_sc1(ob + l15 * 1024 + cB + 16, w1);
    }
    __syncthreads();   // drains vmcnt(0) in every wave (proven r2) + joins WG
    if (tid == 0)
      __hip_atomic_fetch_add(ctr, 1, __ATOMIC_RELAXED,
                             __HIP_MEMORY_SCOPE_AGENT);  // 1 post per WG

    // ---- outputs, off the critical path (after post)
    if (grp == 7 && l15 == 7) {                  // batch 63 row, 8 cols/lane
      #pragma unroll
      for (int r = 0; r < 4; ++r) {
        out[(size_t)(cB + r) * TT + t] = h0[r];
        out[(size_t)(cB + 16 + r) * TT + t] = h1[r];
      }
    }
    if (t == TT - 1 && l15 < 8) {                // final h, coalesced f32x4
      const int br = grp * 8 + l15;
      *(f32x4*)(out + (size_t)NRECN * TT + (size_t)br * NRECN + cB) = h0;
      *(f32x4*)(out + (size_t)NRECN * TT + (size_t)br * NRECN + cB + 16) = h1;
    }
  }
}

extern "C" void kernel_launch(void* const* d_in, const int* in_sizes, int n_in,
                              void* d_out, int out_size, void* d_ws, size_t ws_size,
                              hipStream_t stream) {
  const float* x     = (const float*)d_in[0];
  const float* W_ih  = (const float*)d_in[1];
  const float* W_hh  = (const float*)d_in[2];
  const float* noise = (const float*)d_in[3];
  float* out = (float*)d_out;

  char* ws = (char*)d_ws;
  int* flags = (int*)ws;                         // 8 counters, 64B apart
  _Float16* th = (_Float16*)(ws + 4096);         // [8][2][8][1024] f16 = 256 KB
  // ws usage: 4096 + 262144 = 266,240 bytes. Every byte of each tile is
  // rewritten by the group before it is read -> no th memset needed.

  (void)hipMemsetAsync(flags, 0, 4096, stream);  // deterministic replays

  const size_t lds_bytes = (size_t)136 * 64 * 8 * sizeof(_Float16); // 139,264
  (void)hipFuncSetAttribute((const void*)rnn_scan_kernel,
                            hipFuncAttributeMaxDynamicSharedMemorySize,
                            (int)lds_bytes);

  rnn_scan_kernel<<<dim3(NWG), dim3(128), lds_bytes, stream>>>(
      x, W_ih, W_hh, noise, out, flags, th);
}